// Round 2
// baseline (262.940 us; speedup 1.0000x reference)
//
#include <hip/hip_runtime.h>

// Bilateral 5x5 filter, 3 chained passes on [32,1,512,512] fp32.
// w(dr,dc) = exp2( -(dr^2/(2sx^2) + dc^2/(2sy^2) + (nb-c)^2/(2sr^2)) * log2e )
// out = sum(w*nb)/sum(w); replicate padding.
// Compute-bound on v_exp_f32: structure minimizes VALU slots per neighbor
// (sub, mul, fma, exp2, fma, add) with log2e pre-folded into constants.

#define HWIN 2
#define TX   64                     // threads in x
#define TY   4                      // threads in y
#define PXT  4                      // pixels per thread along x
#define PYT  2                      // pixels per thread along y
#define TILE_W (TX * PXT)           // 256 output cols per block
#define TILE_H (TY * PYT)           // 8 output rows per block
#define LDS_W  (TILE_W + 2*PXT)     // 264 (16B-aligned halo: col0 = x0-4)
#define LDS_H  (TILE_H + 2*HWIN)    // 12

#if __has_builtin(__builtin_amdgcn_exp2f)
#define EXP2(x) __builtin_amdgcn_exp2f(x)
#else
#define EXP2(x) exp2f(x)
#endif
#if __has_builtin(__builtin_amdgcn_rcpf)
#define RCP(x) __builtin_amdgcn_rcpf(x)
#else
#define RCP(x) (1.0f / (x))
#endif

__global__ __launch_bounds__(256, 4)   // VGPR cap 128: 4 blocks(16 waves)/CU
void bilat_pass(const float* __restrict__ in, float* __restrict__ out,
                const float* __restrict__ sxyz, const float* __restrict__ srr,
                int pass, int H, int W)
{
    // Row stride 264 floats = 1056 B (66*16) -> every row 16B-aligned.
    __shared__ __align__(16) float tile[LDS_H][LDS_W];

    const int tx = threadIdx.x, ty = threadIdx.y;
    const int x0 = blockIdx.x * TILE_W;
    const int y0 = blockIdx.y * TILE_H;
    const size_t img_off = (size_t)blockIdx.z * (size_t)H * (size_t)W;
    const float* __restrict__ img = in + img_off;

    // ---- stage tile with replicate clamp (contiguous LDS addresses) ----
    const int lid = ty * TX + tx;   // 0..255
    #pragma unroll
    for (int i = 0; i < (LDS_W * LDS_H + 255) / 256; ++i) {
        int idx = lid + i * 256;
        if (idx < LDS_W * LDS_H) {
            int ly = idx / LDS_W;          // const divisor -> magic mul
            int lx = idx - ly * LDS_W;
            int gy = min(max(y0 + ly - HWIN, 0), H - 1);
            int gx = min(max(x0 + lx - PXT, 0), W - 1);
            ((float*)tile)[idx] = img[(size_t)gy * W + gx];
        }
    }
    __syncthreads();

    // ---- per-pass constants, log2e pre-folded, negated ----
    const float sx = sxyz[2 * pass + 0];
    const float sy = sxyz[2 * pass + 1];
    const float sr = srr[pass];
    const float L2E = 1.4426950408889634f;
    const float ncr = -0.5f / (sr * sr) * L2E;   // * d^2
    const float nax = -0.5f / (sx * sx) * L2E;   // * dr^2
    const float nay = -0.5f / (sy * sy) * L2E;   // * dc^2
    // spatial term for squared offsets {0,1,4} x {0,1,4}
    float nsp[3][3];
    {
        const float sq[3] = {0.f, 1.f, 4.f};
        #pragma unroll
        for (int a = 0; a < 3; ++a)
            #pragma unroll
            for (int b = 0; b < 3; ++b)
                nsp[a][b] = sq[a] * nax + sq[b] * nay;
    }

    // ---- compute PYT x PXT pixels per thread ----
    const int r0 = ty * PYT;                 // top LDS row of 6-row window
    const int cx0 = PXT * tx;                // LDS col of win[0]

    float cen[PYT][PXT];
    #pragma unroll
    for (int q = 0; q < PYT; ++q) {
        const float4 c4 = *(const float4*)&tile[r0 + HWIN + q][cx0 + PXT];
        cen[q][0] = c4.x; cen[q][1] = c4.y; cen[q][2] = c4.z; cen[q][3] = c4.w;
    }
    float num[PYT][PXT] = {}, den[PYT][PXT] = {};

    #pragma unroll
    for (int rr = 0; rr < PYT + 2 * HWIN; ++rr) {      // 6 LDS rows, loaded once
        const float* rowp = &tile[r0 + rr][cx0];
        float win[12];
        *(float4*)&win[0] = *(const float4*)(rowp);
        *(float4*)&win[4] = *(const float4*)(rowp + 4);
        *(float4*)&win[8] = *(const float4*)(rowp + 8);

        #pragma unroll
        for (int q = 0; q < PYT; ++q) {
            const int dr = rr - HWIN - q;
            if (dr < -HWIN || dr > HWIN) continue;     // folded at compile time
            const int a2 = (dr * dr == 4) ? 2 : dr * dr;
            #pragma unroll
            for (int dc = -HWIN; dc <= HWIN; ++dc) {
                const int b2 = (dc * dc == 4) ? 2 : dc * dc;
                const float base = nsp[a2][b2];
                #pragma unroll
                for (int j = 0; j < PXT; ++j) {
                    const float nb = win[PXT + j + dc];
                    if (dr == 0 && dc == 0) {
                        num[q][j] += nb;               // w == 1 exactly
                        den[q][j] += 1.0f;
                    } else {
                        const float d = nb - cen[q][j];
                        const float t = fmaf(d * d, ncr, base);
                        const float w = EXP2(t);
                        num[q][j] = fmaf(w, nb, num[q][j]);
                        den[q][j] += w;
                    }
                }
            }
        }
    }

    // ---- store ----
    const int ox = x0 + cx0;
    #pragma unroll
    for (int q = 0; q < PYT; ++q) {
        const int oy = y0 + r0 + q;
        if (oy < H) {
            if (ox + PXT <= W) {
                float4 o;
                o.x = num[q][0] * RCP(den[q][0]);
                o.y = num[q][1] * RCP(den[q][1]);
                o.z = num[q][2] * RCP(den[q][2]);
                o.w = num[q][3] * RCP(den[q][3]);
                *(float4*)&out[img_off + (size_t)oy * W + ox] = o;
            } else {
                for (int j = 0; j < PXT; ++j)
                    if (ox + j < W)
                        out[img_off + (size_t)oy * W + ox + j] =
                            num[q][j] * RCP(den[q][j]);
            }
        }
    }
}

extern "C" void kernel_launch(void* const* d_in, const int* in_sizes, int n_in,
                              void* d_out, int out_size, void* d_ws, size_t ws_size,
                              hipStream_t stream)
{
    const float* x    = (const float*)d_in[0];
    const float* sxyz = (const float*)d_in[1];   // [3,2]
    const float* sr   = (const float*)d_in[2];   // [3]
    float* out = (float*)d_out;
    float* tmp = (float*)d_ws;                   // 33.5 MB scratch

    const int H = 512, W = 512;
    const int BC = in_sizes[0] / (H * W);        // 32

    dim3 block(TX, TY);
    dim3 grid((W + TILE_W - 1) / TILE_W, (H + TILE_H - 1) / TILE_H, BC);

    // pass 0: x -> out ; pass 1: out -> tmp ; pass 2: tmp -> out
    bilat_pass<<<grid, block, 0, stream>>>(x,   out, sxyz, sr, 0, H, W);
    bilat_pass<<<grid, block, 0, stream>>>(out, tmp, sxyz, sr, 1, H, W);
    bilat_pass<<<grid, block, 0, stream>>>(tmp, out, sxyz, sr, 2, H, W);
}

// Round 3
// 167.434 us; speedup vs baseline: 1.5704x; 1.5704x over previous
//
#include <hip/hip_runtime.h>

// Bilateral 5x5 filter, 3 chained passes on [32,1,512,512] fp32.
// w(dr,dc) = exp2( (dr^2*nax + dc^2*nay) + d^2*ncr ), constants pre-folded
// with -log2e. out = sum(w*nb)/sum(w); replicate padding.
//
// Key optimization: spatial weights are wave-UNIFORM (SGPR), so taps whose
// spatial log2-weight falls below TH2 are skipped by uniform scalar branches
// (no divergence). For this benchmark's sigma=0.5 that prunes the 5x5 to an
// effective 3x3 (8 exps/px instead of 24) and skips the LDS reads of rows
// +-2 entirely. Dropped spatial mass <= 1.7e-3/pass (den>=1), i.e. <=5e-3
// over 3 passes vs the 2e-2 absmax threshold. For large sigma nothing is
// pruned and the kernel is exact.
//
// Round-2 lesson: PYT=2 (8px/thread) cut VALU work 25% but collapsed
// occupancy 72%->37% and regressed. Keep the round-1 wave shape
// (4px/thread, 8192 blocks, 82% VALUBusy) and cut instructions instead.

#define HWIN 2
#define TX   64                     // threads in x
#define TY   4                      // threads in y
#define PXT  4                      // pixels per thread along x
#define TILE_W (TX * PXT)           // 256 output cols per block
#define LDS_W  (TILE_W + 2*PXT)     // 264: col 0 = x0-4 (16B-aligned halo)
#define LDS_H  (TY + 2*HWIN)        // 8 rows

#if __has_builtin(__builtin_amdgcn_exp2f)
#define EXP2(x) __builtin_amdgcn_exp2f(x)
#else
#define EXP2(x) exp2f(x)
#endif
#if __has_builtin(__builtin_amdgcn_rcpf)
#define RCP(x) __builtin_amdgcn_rcpf(x)
#else
#define RCP(x) (1.0f / (x))
#endif

// prune taps with spatial weight < 2^TH2 (uniform branch, error-bounded)
#define TH2 (-10.0f)

__global__ __launch_bounds__(256)
void bilat_pass(const float* __restrict__ in, float* __restrict__ out,
                const float* __restrict__ sxyz, const float* __restrict__ srr,
                int pass, int H, int W)
{
    // Row stride 264 floats = 1056 B (66*16) -> every row 16B-aligned.
    __shared__ __align__(16) float tile[LDS_H][LDS_W];

    const int tx = threadIdx.x, ty = threadIdx.y;
    const int x0 = blockIdx.x * TILE_W;
    const int y0 = blockIdx.y * TY;
    const size_t img_off = (size_t)blockIdx.z * (size_t)H * (size_t)W;
    const float* __restrict__ img = in + img_off;

    // ---- stage tile with replicate clamp (contiguous LDS addresses) ----
    const int lid = ty * TX + tx;   // 0..255
    #pragma unroll
    for (int i = 0; i < (LDS_W * LDS_H + 255) / 256; ++i) {
        int idx = lid + i * 256;
        if (idx < LDS_W * LDS_H) {
            int ly = idx / LDS_W;          // const divisor -> magic mul
            int lx = idx - ly * LDS_W;
            int gy = min(max(y0 + ly - HWIN, 0), H - 1);
            int gx = min(max(x0 + lx - PXT, 0), W - 1);
            ((float*)tile)[idx] = img[(size_t)gy * W + gx];
        }
    }
    __syncthreads();

    // ---- per-pass constants (SGPR), -log2e pre-folded ----
    const float sx = sxyz[2 * pass + 0];
    const float sy = sxyz[2 * pass + 1];
    const float sr = srr[pass];
    const float L2E = 1.4426950408889634f;
    const float ncr = -0.5f / (sr * sr) * L2E;   // * d^2
    const float nax = -0.5f / (sx * sx) * L2E;   // * dr^2
    const float nay = -0.5f / (sy * sy) * L2E;   // * dc^2

    // ---- compute 4 pixels per thread ----
    const int cx0 = PXT * tx;                    // LDS col of win[0]
    const float4 cen4 = *(const float4*)&tile[ty + HWIN][cx0 + PXT];
    const float cen[4] = {cen4.x, cen4.y, cen4.z, cen4.w};
    // center tap: w == 1 exactly
    float num[4] = {cen[0], cen[1], cen[2], cen[3]};
    float den[4] = {1.f, 1.f, 1.f, 1.f};

    #pragma unroll
    for (int dr = -HWIN; dr <= HWIN; ++dr) {
        const float ra = (float)(dr * dr) * nax;         // uniform
        // best live tap in this row: dc=0 for dr!=0, dc=+-1 for dr==0
        const float rbest = dr ? ra : nay;
        if (rbest < TH2) continue;                       // uniform row skip
        const float* rowp = &tile[ty + HWIN + dr][cx0];
        float win[12];
        *(float4*)&win[0] = *(const float4*)(rowp);
        *(float4*)&win[4] = *(const float4*)(rowp + 4);
        *(float4*)&win[8] = *(const float4*)(rowp + 8);

        #pragma unroll
        for (int dc = -HWIN; dc <= HWIN; ++dc) {
            if (dr == 0 && dc == 0) continue;            // center done
            const float base = ra + (float)(dc * dc) * nay;  // uniform
            if (base < TH2) continue;                    // uniform tap skip
            #pragma unroll
            for (int j = 0; j < PXT; ++j) {
                const float nb = win[PXT + j + dc];
                const float d  = nb - cen[j];
                const float t  = fmaf(d * d, ncr, base);
                const float w  = EXP2(t);
                num[j] = fmaf(w, nb, num[j]);
                den[j] += w;
            }
        }
    }

    // ---- store ----
    const int ox = x0 + cx0;
    const int oy = y0 + ty;
    if (oy < H) {
        if (ox + PXT <= W) {
            float4 o;
            o.x = num[0] * RCP(den[0]);
            o.y = num[1] * RCP(den[1]);
            o.z = num[2] * RCP(den[2]);
            o.w = num[3] * RCP(den[3]);
            *(float4*)&out[img_off + (size_t)oy * W + ox] = o;
        } else {
            for (int j = 0; j < PXT; ++j)
                if (ox + j < W)
                    out[img_off + (size_t)oy * W + ox + j] =
                        num[j] * RCP(den[j]);
        }
    }
}

extern "C" void kernel_launch(void* const* d_in, const int* in_sizes, int n_in,
                              void* d_out, int out_size, void* d_ws, size_t ws_size,
                              hipStream_t stream)
{
    const float* x    = (const float*)d_in[0];
    const float* sxyz = (const float*)d_in[1];   // [3,2]
    const float* sr   = (const float*)d_in[2];   // [3]
    float* out = (float*)d_out;
    float* tmp = (float*)d_ws;                   // 33.5 MB scratch

    const int H = 512, W = 512;
    const int BC = in_sizes[0] / (H * W);        // 32

    dim3 block(TX, TY);
    dim3 grid((W + TILE_W - 1) / TILE_W, (H + TY - 1) / TY, BC);

    // pass 0: x -> out ; pass 1: out -> tmp ; pass 2: tmp -> out
    bilat_pass<<<grid, block, 0, stream>>>(x,   out, sxyz, sr, 0, H, W);
    bilat_pass<<<grid, block, 0, stream>>>(out, tmp, sxyz, sr, 1, H, W);
    bilat_pass<<<grid, block, 0, stream>>>(tmp, out, sxyz, sr, 2, H, W);
}